// Round 14
// baseline (84.999 us; speedup 1.0000x reference)
//
#include <hip/hip_runtime.h>
#include <math.h>

#define BB 64
#define LL 256
#define DD 1024
#define NDPAD 512   // padded anti-diagonal count per batch (511 real + 1 pad)
#define LOG2E 1.4426950408889634f
#define LN2   0.6931471805599453f

typedef __attribute__((ext_vector_type(8))) short short8v;
typedef __attribute__((ext_vector_type(4))) float float4v;
typedef __attribute__((ext_vector_type(4))) unsigned int uint4v;

__device__ __forceinline__ unsigned short f2bf(float f) {
    unsigned u = __float_as_uint(f);
    unsigned r = (u + 0x7fffu + ((u >> 16) & 1u)) >> 16;   // RNE
    return (unsigned short)r;
}
__device__ __forceinline__ float bf2f(unsigned short u) {
    return __uint_as_float(((unsigned)u) << 16);
}
// packed RNE convert: dst = (bf16(hi)<<16) | bf16(lo)
__device__ __forceinline__ unsigned cvtpk(float lo, float hi) {
    unsigned r;
    asm("v_cvt_pk_bf16_f32 %0, %1, %2" : "=v"(r) : "v"(lo), "v"(hi));
    return r;
}

// ---------- fused: global_load_lds fp32 staging + in-reg bf16 convert + MFMA ----------
// 128x128 tile, grid (BB, 4) (same-XCD tile group -> L2 merge), 512 threads.
// Waves 0-3 pipeline k<512, waves 4-7 k>=512 (own LDS buffers).
// Staging: global_load_lds width16 (DMA, no VALU/regs/ds_write). LDS stays LINEAR;
// the 16B k-slot of row r is stored at slot^(r&7) via pre-swizzled GLOBAL source,
// so fragment ds_read_b128 at slot (2j)^(r&7) is ~2-way banked (free).
// Fragments read fp32 -> v_cvt_pk_bf16_f32 -> MFMA; row norms accumulate on the
// same fp32 values (wc==0 waves: A rows; wr==0 waves: B rows).
__global__ __launch_bounds__(512) void fused_kernel(const float* __restrict__ S,
                                                    const float* __restrict__ T,
                                                    unsigned short* __restrict__ Dd) {
    __shared__ float lds[2][2][2][128 * 32];   // [pipe][buf][A/B][row*32+k] fp32, 128 KB
    __shared__ float nrmP[2][2][128];          // partial norms [pipe][side][row]

    const int b    = blockIdx.x;
    const int tile = blockIdx.y;
    const int i0 = (tile & 1) * 128;
    const int j0 = (tile >> 1) * 128;
    const int tid = threadIdx.x, w = tid >> 6, lane = tid & 63;
    const int p = w >> 2;                    // K-pipeline (0: k<512, 1: k>=512)
    const int q = w & 3;                     // role within pipeline
    const int wr = q >> 1, wc = q & 1;
    const int kbase = p * 512;

    const float* Sg = S + ((size_t)b * LL + i0) * DD;
    const float* Tg = T + ((size_t)b * LL + j0) * DD;

    // staging: op o covers rows q*32+8o .. +8; lane fills LDS slot (lane&7) of
    // row +(lane>>3); global k-slot = (lane&7)^(row&7)  (inverse XOR swizzle)
    const int srow = lane >> 3;
    const int gsl  = lane & 7;

    float4v acc[4][4];
    const float4v fzero = {0.f, 0.f, 0.f, 0.f};
    #pragma unroll
    for (int mi = 0; mi < 4; ++mi)
        #pragma unroll
        for (int ni = 0; ni < 4; ++ni) acc[mi][ni] = fzero;

    float nsA[4] = {0.f, 0.f, 0.f, 0.f};
    float nsB[4] = {0.f, 0.f, 0.f, 0.f};

    auto stage = [&](int buf, int kt) {
        #pragma unroll
        for (int o = 0; o < 4; ++o) {
            int r  = q * 32 + o * 8 + srow;
            int gs = gsl ^ (r & 7);
            __builtin_amdgcn_global_load_lds(
                (const __attribute__((address_space(1))) void*)(Sg + (size_t)r * DD + kbase + kt * 32 + gs * 4),
                (__attribute__((address_space(3))) void*)(&lds[p][buf][0][(q * 32 + o * 8) * 32]),
                16, 0, 0);
            __builtin_amdgcn_global_load_lds(
                (const __attribute__((address_space(1))) void*)(Tg + (size_t)r * DD + kbase + kt * 32 + gs * 4),
                (__attribute__((address_space(3))) void*)(&lds[p][buf][1][(q * 32 + o * 8) * 32]),
                16, 0, 0);
        }
    };

    const int j2 = (lane >> 4) * 2;          // global 16B-slot pair for this lane's k-slice

    auto compute = [&](int buf) {
        const float* LA = &lds[p][buf][0][0];
        const float* LB = &lds[p][buf][1][0];
        short8v af[4], bf[4];
        #pragma unroll
        for (int mi = 0; mi < 4; ++mi) {
            int r = wr * 64 + mi * 16 + (lane & 15);
            float4 e0 = *(const float4*)(LA + r * 32 + ((j2    ) ^ (r & 7)) * 4);
            float4 e1 = *(const float4*)(LA + r * 32 + ((j2 + 1) ^ (r & 7)) * 4);
            if (wc == 0)
                nsA[mi] += e0.x * e0.x + e0.y * e0.y + e0.z * e0.z + e0.w * e0.w
                         + e1.x * e1.x + e1.y * e1.y + e1.z * e1.z + e1.w * e1.w;
            union { uint4v u; short8v s; } cv;
            cv.u[0] = cvtpk(e0.x, e0.y); cv.u[1] = cvtpk(e0.z, e0.w);
            cv.u[2] = cvtpk(e1.x, e1.y); cv.u[3] = cvtpk(e1.z, e1.w);
            af[mi] = cv.s;
        }
        #pragma unroll
        for (int ni = 0; ni < 4; ++ni) {
            int r = wc * 64 + ni * 16 + (lane & 15);
            float4 e0 = *(const float4*)(LB + r * 32 + ((j2    ) ^ (r & 7)) * 4);
            float4 e1 = *(const float4*)(LB + r * 32 + ((j2 + 1) ^ (r & 7)) * 4);
            if (wr == 0)
                nsB[ni] += e0.x * e0.x + e0.y * e0.y + e0.z * e0.z + e0.w * e0.w
                         + e1.x * e1.x + e1.y * e1.y + e1.z * e1.z + e1.w * e1.w;
            union { uint4v u; short8v s; } cv;
            cv.u[0] = cvtpk(e0.x, e0.y); cv.u[1] = cvtpk(e0.z, e0.w);
            cv.u[2] = cvtpk(e1.x, e1.y); cv.u[3] = cvtpk(e1.z, e1.w);
            bf[ni] = cv.s;
        }
        #pragma unroll
        for (int mi = 0; mi < 4; ++mi)
            #pragma unroll
            for (int ni = 0; ni < 4; ++ni)
                acc[mi][ni] = __builtin_amdgcn_mfma_f32_16x16x32_bf16(af[mi], bf[ni],
                                                                      acc[mi][ni], 0, 0, 0);
    };

    stage(0, 0);
    for (int kt = 0; kt < 16; ++kt) {
        int cur = kt & 1;
        __syncthreads();                      // buf[cur] DMA drained; prev reads done
        if (kt < 15) stage(cur ^ 1, kt + 1);  // DMA flies under compute
        compute(cur);
    }

    // row norms: sum the 4 k-slice groups (lane>>4) via xor-shuffles
    if (wc == 0) {
        #pragma unroll
        for (int mi = 0; mi < 4; ++mi) {
            float s = nsA[mi];
            s += __shfl_xor(s, 16, 64);
            s += __shfl_xor(s, 32, 64);
            if (lane < 16) nrmP[p][0][wr * 64 + mi * 16 + lane] = s;
        }
    }
    if (wr == 0) {
        #pragma unroll
        for (int ni = 0; ni < 4; ++ni) {
            float s = nsB[ni];
            s += __shfl_xor(s, 16, 64);
            s += __shfl_xor(s, 32, 64);
            if (lane < 16) nrmP[p][1][wc * 64 + ni * 16 + lane] = s;
        }
    }
    __syncthreads();                          // staging reads done; norms visible

    // combine pipeline-1 partial accs into pipeline-0 (reuse staging LDS)
    float* cb = &lds[0][0][0][0];
    if (p == 1) {
        #pragma unroll
        for (int mi = 0; mi < 4; ++mi)
            #pragma unroll
            for (int ni = 0; ni < 4; ++ni)
                *(float4v*)(cb + q * 4096 + (mi * 4 + ni) * 256 + lane * 4) = acc[mi][ni];
    }
    __syncthreads();

    if (p == 0) {
        #pragma unroll
        for (int mi = 0; mi < 4; ++mi)
            #pragma unroll
            for (int ni = 0; ni < 4; ++ni)
                acc[mi][ni] += *(const float4v*)(cb + q * 4096 + (mi * 4 + ni) * 256 + lane * 4);

        // epilogue: sq = ||s||^2 + ||t||^2 - 2*dot -> sqrt -> bf16 * LOG2E, diag-major
        const int r0 = (lane >> 4) * 4;
        const int cf = lane & 15;
        unsigned short* Db = Dd + (size_t)b * NDPAD * 256;
        #pragma unroll
        for (int mi = 0; mi < 4; ++mi) {
            #pragma unroll
            for (int ni = 0; ni < 4; ++ni) {
                int lj = wc * 64 + ni * 16 + cf;
                float tj = nrmP[0][1][lj] + nrmP[1][1][lj];
                int j = j0 + lj;
                #pragma unroll
                for (int rg = 0; rg < 4; ++rg) {
                    int li = wr * 64 + mi * 16 + r0 + rg;
                    float sq = nrmP[0][0][li] + nrmP[1][0][li] + tj - 2.0f * acc[mi][ni][rg];
                    float dv = sqrtf(fmaxf(sq, 1e-12f));
                    int i = i0 + li;
                    Db[(size_t)(i + j) * 256 + j] = f2bf(dv * LOG2E);
                }
            }
        }
    }
}

// ---------- soft-DTW DP: 4 waves per batch, chunk-skewed wavefront ----------
// Wave w owns cols 64w+1..64w+64 (1 cell/lane). Wave w processes 16-diagonal
// chunk c during round r=c+w; boundary col values flow w -> w+1 via LDS with a
// one-round skew, so sync is ONE barrier per 16 steps.

// lane i <- lane i-1 via DPP wave_shr:1; lane 0 <- fill (old value, bound_ctrl=0)
__device__ __forceinline__ float wshr1(float src, float fill) {
    return __int_as_float(__builtin_amdgcn_update_dpp(
        __float_as_int(fill), __float_as_int(src), 0x138, 0xF, 0xF, false));
}

__global__ __launch_bounds__(256) void sdtw_kernel(const unsigned short* __restrict__ Dg,
                                                   float* __restrict__ res) {
    __shared__ unsigned short sd[8][16 * 256];   // 8 chunk buffers x 8 KB = 64 KB
    __shared__ float bbuf[3][2][16];             // boundary rings (writer waves 0..2)
    const int b = blockIdx.x;
    const int tid = threadIdx.x;
    const int w = tid >> 6;                      // wave 0..3
    const int lane = tid & 63;
    const float INF = INFINITY;
    const unsigned short* Db = Dg + (size_t)b * NDPAD * 256;

    auto prefetch = [&](int c) {
        #pragma unroll
        for (int q = 0; q < 8; ++q) {
            __builtin_amdgcn_global_load_lds(
                (const __attribute__((address_space(1))) void*)(Db + (size_t)c * 4096 + q * 512 + lane * 8),
                (__attribute__((address_space(3))) void*)(&sd[c & 7][q * 512]),
                16, 0, 0);
        }
    };

    const int col0 = 64 * w + lane;              // 0-based column (j-1)
    float rm1 = INF, rm2 = INF;
    float p2carry = (tid == 0) ? 0.0f : INF;     // R(0,0) seed for wave0 lane0
    float bcarry = INF;

    if (w == 0) {
        prefetch(0);
        prefetch(1);
        asm volatile("s_waitcnt vmcnt(8)" ::: "memory");   // chunk 0 landed
    }
    asm volatile("s_waitcnt lgkmcnt(0)" ::: "memory");
    __builtin_amdgcn_s_barrier();

    for (int r = 0; r < 35; ++r) {
        if (w == 0 && r + 2 < 32) prefetch(r + 2);
        const int c = r - w;
        if (0 <= c && c < 32) {
            const unsigned short* Lp = &sd[c & 7][0];
            float dv[16];
            #pragma unroll
            for (int q = 0; q < 16; ++q)
                dv[q] = bf2f(Lp[q * 256 + col0]);

            float bv[16];
            if (w == 0) {
                #pragma unroll
                for (int q = 0; q < 16; ++q) bv[q] = INF;
            } else {
                const float4* bp4 = (const float4*)&bbuf[w - 1][c & 1][0];
                float4 b0 = bp4[0], b1 = bp4[1], b2 = bp4[2], b3 = bp4[3];
                bv[0] = bcarry;
                bv[1] = b0.x;  bv[2] = b0.y;  bv[3] = b0.z;  bv[4] = b0.w;
                bv[5] = b1.x;  bv[6] = b1.y;  bv[7] = b1.z;  bv[8] = b1.w;
                bv[9] = b2.x;  bv[10] = b2.y; bv[11] = b2.z; bv[12] = b2.w;
                bv[13] = b3.x; bv[14] = b3.y; bv[15] = b3.z;
                bcarry = b3.w;
            }
            asm volatile("s_waitcnt lgkmcnt(0)" ::: "memory");
            __builtin_amdgcn_sched_barrier(0);

            const int ibase = 16 * c - col0;     // (i-1) at q=0
            float bb[16];
            #pragma unroll
            for (int q = 0; q < 16; ++q) {
                float p1 = wshr1(rm1, bv[q]);    // left neighbor's diag d-1
                float p2 = p2carry;              // left neighbor's diag d-2
                p2carry = p1;
                float m   = fminf(p2, fminf(rm1, p1));
                float mid = __builtin_amdgcn_fmed3f(p2, rm1, p1);
                float M   = fmaxf(p2, fmaxf(rm1, p1));
                float s   = (__builtin_amdgcn_exp2f(m - mid) +
                             __builtin_amdgcn_exp2f(m - M)) + 1.0f;
                float rcv = dv[q] + m - __builtin_amdgcn_logf(s);
                bool valid = (unsigned)(ibase + q) < 256u;
                rcv = valid ? rcv : INF;
                rm2 = rm1;
                rm1 = rcv;
                bb[q] = rcv;
            }
            if (w < 3 && lane == 63) {           // publish 16 boundary values
                float4* op = (float4*)&bbuf[w][c & 1][0];
                op[0] = make_float4(bb[0], bb[1], bb[2], bb[3]);
                op[1] = make_float4(bb[4], bb[5], bb[6], bb[7]);
                op[2] = make_float4(bb[8], bb[9], bb[10], bb[11]);
                op[3] = make_float4(bb[12], bb[13], bb[14], bb[15]);
            }
        }
        if (w == 0) {
            if (r < 30) asm volatile("s_waitcnt vmcnt(8)" ::: "memory");
            else        asm volatile("s_waitcnt vmcnt(0)" ::: "memory");
        }
        asm volatile("s_waitcnt lgkmcnt(0)" ::: "memory");
        __builtin_amdgcn_s_barrier();
    }
    // After dummy step d=513, rm2 of wave3 lane63 = R(256,256)
    if (tid == 255) res[b] = rm2 * LN2;
}

// ---------- final mean over batches ----------
__global__ void reduce_kernel(const float* __restrict__ res, float* __restrict__ out) {
    int t = threadIdx.x;
    float v = res[t];
    #pragma unroll
    for (int off = 32; off; off >>= 1) v += __shfl_down(v, off, 64);
    if (t == 0) out[0] = v * (1.0f / BB);
}

extern "C" void kernel_launch(void* const* d_in, const int* in_sizes, int n_in,
                              void* d_out, int out_size, void* d_ws, size_t ws_size,
                              hipStream_t stream) {
    const float* S = (const float*)d_in[0];
    const float* T = (const float*)d_in[1];

    const size_t nDiag = (size_t)BB * NDPAD * 256;   // 8,388,608 ushorts (16.8 MB)
    unsigned short* diag = (unsigned short*)d_ws;
    float* rsv = (float*)(diag + nDiag);

    fused_kernel<<<dim3(BB, 4), 512, 0, stream>>>(S, T, diag);
    sdtw_kernel<<<BB, 256, 0, stream>>>(diag, rsv);
    reduce_kernel<<<1, 64, 0, stream>>>(rsv, (float*)d_out);
}

// Round 15
// 75.275 us; speedup vs baseline: 1.1292x; 1.1292x over previous
//
#include <hip/hip_runtime.h>
#include <math.h>

#define BB 64
#define LL 256
#define DD 1024
#define NDPAD 512   // padded anti-diagonal count per batch (511 real + 1 pad)
#define BK 32
#define LOG2E 1.4426950408889634f
#define LN2   0.6931471805599453f

typedef __attribute__((ext_vector_type(8))) short short8v;
typedef __attribute__((ext_vector_type(4))) float float4v;

__device__ __forceinline__ unsigned short f2bf(float f) {
    unsigned u = __float_as_uint(f);
    unsigned r = (u + 0x7fffu + ((u >> 16) & 1u)) >> 16;   // RNE
    return (unsigned short)r;
}
__device__ __forceinline__ float bf2f(unsigned short u) {
    return __uint_as_float(((unsigned)u) << 16);
}
// packed RNE convert: dst = (bf16(hi)<<16) | bf16(lo)
__device__ __forceinline__ unsigned cvtpk(float lo, float hi) {
    unsigned r;
    asm("v_cvt_pk_bf16_f32 %0, %1, %2" : "=v"(r) : "v"(lo), "v"(hi));
    return r;
}

// ---------- fused: fp32 load -> bf16 LDS staging + row norms + MFMA dist GEMM ----------
// 128x128 tile, grid (BB, 4) (same-XCD tile group -> L2 merge), 512 threads.
// In-block K-split: waves 0-3 pipeline k<512, waves 4-7 k>=512.
// LDS layout: [row][32 bf16], 64B row stride; 16B slot s of row r lives at
// phys_slot = s ^ ((r>>1)&3). This makes BOTH the staging ds_write_b128 pattern
// (4 consecutive rows x 4 slots per quarter-wave) and the fragment ds_read_b128
// pattern (16 consecutive rows, fixed k-group) hit each bank-quad exactly twice
// = the b128 minimum (bank quad = phys_slot + 4*(r&1) since 64B stride).
// K-loop barriers: lgkmcnt(0) + raw s_barrier (no vmcnt drain -> prefetch flies).
__global__ __launch_bounds__(512) void fused_kernel(const float* __restrict__ S,
                                                    const float* __restrict__ T,
                                                    unsigned short* __restrict__ Dd) {
    __shared__ unsigned short lds[2][2][2][128 * BK];   // [pipe][buf][A/B], 64 KB
    __shared__ float nrmP[2][2][128];                   // partial norms [pipe][side][row]

    const int b    = blockIdx.x;
    const int tile = blockIdx.y;
    const int i0 = (tile & 1) * 128;
    const int j0 = (tile >> 1) * 128;
    const int tid = threadIdx.x, w = tid >> 6, lane = tid & 63;
    const int p = w >> 2;                    // K-pipeline (0: k<512, 1: k>=512)
    const int q = w & 3;                     // role within pipeline
    const int wr = q >> 1, wc = q & 1;
    const int kbase = p * 512;

    const float* Sg = S + ((size_t)b * LL + i0) * DD;
    const float* Tg = T + ((size_t)b * LL + j0) * DD;

    const int sr   = q * 16 + (lane >> 2);   // staging row within 64-row half
    const int slot = lane & 3;               // lds PHYS k-slot this lane fills
    const int kb   = slot ^ ((sr >> 1) & 3); // GLOBAL k-slot (conflict-free swizzle)

    float4v acc[4][4];
    const float4v fzero = {0.f, 0.f, 0.f, 0.f};
    #pragma unroll
    for (int mi = 0; mi < 4; ++mi)
        #pragma unroll
        for (int ni = 0; ni < 4; ++ni) acc[mi][ni] = fzero;

    struct Stg { float4 a[2][2]; float4 bb[2][2]; };   // [half n][8-float piece]
    Stg st0, st1;
    float ns[2][2] = {};                      // norm accum [side][n]

    auto issue = [&](Stg& s, int kt) {
        const float* pa = Sg + (size_t)sr * DD + kbase + kt * BK + kb * 8;
        const float* pb = Tg + (size_t)sr * DD + kbase + kt * BK + kb * 8;
        s.a[0][0]  = *(const float4*)(pa);
        s.a[0][1]  = *(const float4*)(pa + 4);
        s.a[1][0]  = *(const float4*)(pa + 64 * DD);
        s.a[1][1]  = *(const float4*)(pa + 64 * DD + 4);
        s.bb[0][0] = *(const float4*)(pb);
        s.bb[0][1] = *(const float4*)(pb + 4);
        s.bb[1][0] = *(const float4*)(pb + 64 * DD);
        s.bb[1][1] = *(const float4*)(pb + 64 * DD + 4);
    };

    auto cvtwrite = [&](const float4& v0, const float4& v1, unsigned short* dst, float& nacc) {
        nacc += v0.x * v0.x + v0.y * v0.y + v0.z * v0.z + v0.w * v0.w
              + v1.x * v1.x + v1.y * v1.y + v1.z * v1.z + v1.w * v1.w;
        uint4 o;
        o.x = cvtpk(v0.x, v0.y);
        o.y = cvtpk(v0.z, v0.w);
        o.z = cvtpk(v1.x, v1.y);
        o.w = cvtpk(v1.z, v1.w);
        *(uint4*)dst = o;
    };

    auto commit = [&](Stg& s, int buf) {
        #pragma unroll
        for (int n = 0; n < 2; ++n) {
            // note: row = n*64+sr; (row>>1)&3 == (sr>>1)&3 (64 offset keeps bits 1-2)
            cvtwrite(s.a[n][0],  s.a[n][1],  &lds[p][buf][0][(n * 64 + sr) * BK + slot * 8], ns[0][n]);
            cvtwrite(s.bb[n][0], s.bb[n][1], &lds[p][buf][1][(n * 64 + sr) * BK + slot * 8], ns[1][n]);
        }
    };

    auto compute = [&](int buf) {
        const unsigned short* LA = &lds[p][buf][0][0];
        const unsigned short* LB = &lds[p][buf][1][0];
        short8v af[4], bf[4];
        #pragma unroll
        for (int mi = 0; mi < 4; ++mi) {
            int row = wr * 64 + mi * 16 + (lane & 15);
            int kbf = (lane >> 4) ^ ((row >> 1) & 3);   // conflict-free read swizzle
            af[mi] = *(const short8v*)(LA + row * BK + kbf * 8);
        }
        #pragma unroll
        for (int ni = 0; ni < 4; ++ni) {
            int row = wc * 64 + ni * 16 + (lane & 15);
            int kbf = (lane >> 4) ^ ((row >> 1) & 3);
            bf[ni] = *(const short8v*)(LB + row * BK + kbf * 8);
        }
        #pragma unroll
        for (int mi = 0; mi < 4; ++mi)
            #pragma unroll
            for (int ni = 0; ni < 4; ++ni)
                acc[mi][ni] = __builtin_amdgcn_mfma_f32_16x16x32_bf16(af[mi], bf[ni],
                                                                      acc[mi][ni], 0, 0, 0);
    };

    // k-loop barrier: drain ONLY lgkm (own LDS ops); leave global loads in flight.
    auto phase_barrier = [&]() {
        asm volatile("s_waitcnt lgkmcnt(0)" ::: "memory");
        __builtin_amdgcn_s_barrier();
        __builtin_amdgcn_sched_barrier(0);
    };

    issue(st0, 0);
    for (int kt2 = 0; kt2 < 16; kt2 += 2) {
        issue(st1, kt2 + 1);
        commit(st0, 0);
        phase_barrier();
        compute(0);
        if (kt2 + 2 < 16) issue(st0, kt2 + 2);
        commit(st1, 1);
        phase_barrier();
        compute(1);
    }

    // partial row norms: reduce across the 4 slot-lanes of each row group
    #pragma unroll
    for (int side = 0; side < 2; ++side)
        #pragma unroll
        for (int n = 0; n < 2; ++n) {
            float s = ns[side][n];
            s += __shfl_xor(s, 1, 64);
            s += __shfl_xor(s, 2, 64);
            if (slot == 0) nrmP[p][side][n * 64 + sr] = s;
        }
    __syncthreads();                         // staging reads done; norms visible

    // combine pipeline-1 partial accs into pipeline-0 (reuse staging LDS, 64 KB)
    float* cb = (float*)&lds[0][0][0][0];
    if (p == 1) {
        #pragma unroll
        for (int mi = 0; mi < 4; ++mi)
            #pragma unroll
            for (int ni = 0; ni < 4; ++ni)
                *(float4v*)(cb + q * 4096 + (mi * 4 + ni) * 256 + lane * 4) = acc[mi][ni];
    }
    __syncthreads();

    if (p == 0) {
        #pragma unroll
        for (int mi = 0; mi < 4; ++mi)
            #pragma unroll
            for (int ni = 0; ni < 4; ++ni)
                acc[mi][ni] += *(const float4v*)(cb + q * 4096 + (mi * 4 + ni) * 256 + lane * 4);

        // epilogue: sq = ||s||^2 + ||t||^2 - 2*dot -> sqrt -> bf16 * LOG2E, diag-major
        const int r0 = (lane >> 4) * 4;
        const int cf = lane & 15;
        unsigned short* Db = Dd + (size_t)b * NDPAD * 256;
        #pragma unroll
        for (int mi = 0; mi < 4; ++mi) {
            #pragma unroll
            for (int ni = 0; ni < 4; ++ni) {
                int lj = wc * 64 + ni * 16 + cf;
                float tj = nrmP[0][1][lj] + nrmP[1][1][lj];
                int j = j0 + lj;
                #pragma unroll
                for (int rg = 0; rg < 4; ++rg) {
                    int li = wr * 64 + mi * 16 + r0 + rg;
                    float sq = nrmP[0][0][li] + nrmP[1][0][li] + tj - 2.0f * acc[mi][ni][rg];
                    float dv = sqrtf(fmaxf(sq, 1e-12f));
                    int i = i0 + li;
                    Db[(size_t)(i + j) * 256 + j] = f2bf(dv * LOG2E);
                }
            }
        }
    }
}

// ---------- soft-DTW DP: 4 waves per batch, chunk-skewed wavefront ----------
// Wave w owns cols 64w+1..64w+64 (1 cell/lane). Wave w processes 16-diagonal
// chunk c during round r=c+w; boundary col values flow w -> w+1 via LDS with a
// one-round skew, so sync is ONE barrier per 16 steps.

// lane i <- lane i-1 via DPP wave_shr:1; lane 0 <- fill (old value, bound_ctrl=0)
__device__ __forceinline__ float wshr1(float src, float fill) {
    return __int_as_float(__builtin_amdgcn_update_dpp(
        __float_as_int(fill), __float_as_int(src), 0x138, 0xF, 0xF, false));
}

__global__ __launch_bounds__(256) void sdtw_kernel(const unsigned short* __restrict__ Dg,
                                                   float* __restrict__ res) {
    __shared__ unsigned short sd[8][16 * 256];   // 8 chunk buffers x 8 KB = 64 KB
    __shared__ float bbuf[3][2][16];             // boundary rings (writer waves 0..2)
    const int b = blockIdx.x;
    const int tid = threadIdx.x;
    const int w = tid >> 6;                      // wave 0..3
    const int lane = tid & 63;
    const float INF = INFINITY;
    const unsigned short* Db = Dg + (size_t)b * NDPAD * 256;

    auto prefetch = [&](int c) {
        #pragma unroll
        for (int q = 0; q < 8; ++q) {
            __builtin_amdgcn_global_load_lds(
                (const __attribute__((address_space(1))) void*)(Db + (size_t)c * 4096 + q * 512 + lane * 8),
                (__attribute__((address_space(3))) void*)(&sd[c & 7][q * 512]),
                16, 0, 0);
        }
    };

    const int col0 = 64 * w + lane;              // 0-based column (j-1)
    float rm1 = INF, rm2 = INF;
    float p2carry = (tid == 0) ? 0.0f : INF;     // R(0,0) seed for wave0 lane0
    float bcarry = INF;

    if (w == 0) {
        prefetch(0);
        prefetch(1);
        asm volatile("s_waitcnt vmcnt(8)" ::: "memory");   // chunk 0 landed
    }
    asm volatile("s_waitcnt lgkmcnt(0)" ::: "memory");
    __builtin_amdgcn_s_barrier();

    for (int r = 0; r < 35; ++r) {
        if (w == 0 && r + 2 < 32) prefetch(r + 2);
        const int c = r - w;
        if (0 <= c && c < 32) {
            const unsigned short* Lp = &sd[c & 7][0];
            float dv[16];
            #pragma unroll
            for (int q = 0; q < 16; ++q)
                dv[q] = bf2f(Lp[q * 256 + col0]);

            float bv[16];
            if (w == 0) {
                #pragma unroll
                for (int q = 0; q < 16; ++q) bv[q] = INF;
            } else {
                const float4* bp4 = (const float4*)&bbuf[w - 1][c & 1][0];
                float4 b0 = bp4[0], b1 = bp4[1], b2 = bp4[2], b3 = bp4[3];
                bv[0] = bcarry;
                bv[1] = b0.x;  bv[2] = b0.y;  bv[3] = b0.z;  bv[4] = b0.w;
                bv[5] = b1.x;  bv[6] = b1.y;  bv[7] = b1.z;  bv[8] = b1.w;
                bv[9] = b2.x;  bv[10] = b2.y; bv[11] = b2.z; bv[12] = b2.w;
                bv[13] = b3.x; bv[14] = b3.y; bv[15] = b3.z;
                bcarry = b3.w;
            }
            asm volatile("s_waitcnt lgkmcnt(0)" ::: "memory");
            __builtin_amdgcn_sched_barrier(0);

            const int ibase = 16 * c - col0;     // (i-1) at q=0
            float bb[16];
            #pragma unroll
            for (int q = 0; q < 16; ++q) {
                float p1 = wshr1(rm1, bv[q]);    // left neighbor's diag d-1
                float p2 = p2carry;              // left neighbor's diag d-2
                p2carry = p1;
                float m   = fminf(p2, fminf(rm1, p1));
                float mid = __builtin_amdgcn_fmed3f(p2, rm1, p1);
                float M   = fmaxf(p2, fmaxf(rm1, p1));
                float s   = (__builtin_amdgcn_exp2f(m - mid) +
                             __builtin_amdgcn_exp2f(m - M)) + 1.0f;
                float rcv = dv[q] + m - __builtin_amdgcn_logf(s);
                bool valid = (unsigned)(ibase + q) < 256u;
                rcv = valid ? rcv : INF;
                rm2 = rm1;
                rm1 = rcv;
                bb[q] = rcv;
            }
            if (w < 3 && lane == 63) {           // publish 16 boundary values
                float4* op = (float4*)&bbuf[w][c & 1][0];
                op[0] = make_float4(bb[0], bb[1], bb[2], bb[3]);
                op[1] = make_float4(bb[4], bb[5], bb[6], bb[7]);
                op[2] = make_float4(bb[8], bb[9], bb[10], bb[11]);
                op[3] = make_float4(bb[12], bb[13], bb[14], bb[15]);
            }
        }
        if (w == 0) {
            if (r < 30) asm volatile("s_waitcnt vmcnt(8)" ::: "memory");
            else        asm volatile("s_waitcnt vmcnt(0)" ::: "memory");
        }
        asm volatile("s_waitcnt lgkmcnt(0)" ::: "memory");
        __builtin_amdgcn_s_barrier();
    }
    // After dummy step d=513, rm2 of wave3 lane63 = R(256,256)
    if (tid == 255) res[b] = rm2 * LN2;
}

// ---------- final mean over batches ----------
__global__ void reduce_kernel(const float* __restrict__ res, float* __restrict__ out) {
    int t = threadIdx.x;
    float v = res[t];
    #pragma unroll
    for (int off = 32; off; off >>= 1) v += __shfl_down(v, off, 64);
    if (t == 0) out[0] = v * (1.0f / BB);
}

extern "C" void kernel_launch(void* const* d_in, const int* in_sizes, int n_in,
                              void* d_out, int out_size, void* d_ws, size_t ws_size,
                              hipStream_t stream) {
    const float* S = (const float*)d_in[0];
    const float* T = (const float*)d_in[1];

    const size_t nDiag = (size_t)BB * NDPAD * 256;   // 8,388,608 ushorts (16.8 MB)
    unsigned short* diag = (unsigned short*)d_ws;
    float* rsv = (float*)(diag + nDiag);

    fused_kernel<<<dim3(BB, 4), 512, 0, stream>>>(S, T, diag);
    sdtw_kernel<<<BB, 256, 0, stream>>>(diag, rsv);
    reduce_kernel<<<1, 64, 0, stream>>>(rsv, (float*)d_out);
}